// Round 1
// baseline (690.181 us; speedup 1.0000x reference)
//
#include <hip/hip_runtime.h>
#include <math.h>

// GaussianScaleReadout: y[b,o] = sum_k alpha[b,k] * (sum_c h[b,c,k]*w[k,o,c] + bias[k,o])
// Memory-bound on h (512 MiB). One wave per query b; h[b,:,:] is 1024 contiguous
// floats -> 4 coalesced float4 wave-loads. Weights (12 KiB) preloaded to VGPRs
// once per wave (48 floats/lane), amortized over the grid-stride loop.

#define C_H   128
#define KSC   8

constexpr int NBLOCKS  = 2048;   // 8 blocks/CU nominal; grid-stride
constexpr int NTHREADS = 256;    // 4 waves/block
constexpr int NWAVES   = NBLOCKS * NTHREADS / 64;  // 8192

__global__ __launch_bounds__(NTHREADS)
void gsr_kernel(const float* __restrict__ h,      // [BQ, C_H, K]
                const float* __restrict__ cell,   // [BQ, 2]
                const float* __restrict__ w,      // [K, 3, C_H]
                const float* __restrict__ bias,   // [K, 3]
                float* __restrict__ out,          // [BQ, 3]
                int bq)
{
    const int lane   = threadIdx.x & 63;
    const int waveId = blockIdx.x * (NTHREADS / 64) + (threadIdx.x >> 6);

    // ---- one-time per-wave weight preload into registers ----
    // element j = i*256 + lane*4 + e  (j = c*8 + k):
    //   k = (lane&1)*4 + e      (independent of i)
    //   c = i*32 + (lane>>1)
    const int kbase = (lane & 1) * 4;
    const int chalf = lane >> 1;
    float wreg[16][3];
    #pragma unroll
    for (int i = 0; i < 4; ++i) {
        #pragma unroll
        for (int e = 0; e < 4; ++e) {
            const int k = kbase + e;
            const int c = i * 32 + chalf;
            #pragma unroll
            for (int o = 0; o < 3; ++o)
                wreg[i*4+e][o] = w[k * (3*C_H) + o * C_H + c];
        }
    }
    // bias fragments: lane 0 covers k=0..3, lane 1 covers k=4..7, others zero.
    float breg[4][3];
    #pragma unroll
    for (int e = 0; e < 4; ++e)
        #pragma unroll
        for (int o = 0; o < 3; ++o)
            breg[e][o] = (lane < 2) ? bias[(kbase + e) * 3 + o] : 0.0f;

    const float inv_two_sigma_sq = 0.78125f;            // 1 / (2*0.8^2)
    const float log_2_over_inp   = -4.8520302639196171f; // log(2/256)
    const float seven_over_log30 = 2.0580814087539097f;  // 7 / log(30)

    for (int b = waveId; b < bq; b += NWAVES) {
        // ---- tau ----
        const float c0 = cell[2*b + 0];
        const float c1 = cell[2*b + 1];
        const float geo = fmaxf(sqrtf(c0 * c1), 1e-10f);
        const float log_s = log_2_over_inp - __logf(geo);
        float tau = seven_over_log30 * log_s;
        tau = fminf(fmaxf(tau, 0.0f), 7.0f);

        // ---- alpha (Gaussian softmax over k) ----
        float ek[8], s = 0.0f;
        #pragma unroll
        for (int k = 0; k < 8; ++k) {
            const float d = (float)k - tau;
            ek[k] = __expf(-d * d * inv_two_sigma_sq);
            s += ek[k];
        }
        const float inv = 1.0f / s;
        float al[4];   // the 4 alphas this lane's elements use (k = kbase+e)
        #pragma unroll
        for (int e = 0; e < 4; ++e)
            al[e] = ((lane & 1) ? ek[4 + e] : ek[e]) * inv;

        // ---- load this query's h (1024 contiguous floats) ----
        const float4* hp = (const float4*)(h + (size_t)b * (C_H * KSC));
        float4 hv[4];
        #pragma unroll
        for (int i = 0; i < 4; ++i)
            hv[i] = hp[i * 64 + lane];

        // ---- accumulate: acc[o] = sum alpha_k * h * w  (+ bias via lanes 0/1) ----
        float acc[3];
        #pragma unroll
        for (int o = 0; o < 3; ++o) {
            acc[o] = al[0] * breg[0][o];
            #pragma unroll
            for (int e = 1; e < 4; ++e)
                acc[o] = fmaf(al[e], breg[e][o], acc[o]);
        }
        #pragma unroll
        for (int i = 0; i < 4; ++i) {
            const float he[4] = {hv[i].x, hv[i].y, hv[i].z, hv[i].w};
            #pragma unroll
            for (int e = 0; e < 4; ++e) {
                const float ha = he[e] * al[e];
                #pragma unroll
                for (int o = 0; o < 3; ++o)
                    acc[o] = fmaf(ha, wreg[i*4+e][o], acc[o]);
            }
        }

        // ---- wave butterfly reduction over 64 lanes ----
        #pragma unroll
        for (int off = 32; off > 0; off >>= 1) {
            acc[0] += __shfl_xor(acc[0], off, 64);
            acc[1] += __shfl_xor(acc[1], off, 64);
            acc[2] += __shfl_xor(acc[2], off, 64);
        }

        if (lane == 0) {
            out[(size_t)b * 3 + 0] = acc[0];
            out[(size_t)b * 3 + 1] = acc[1];
            out[(size_t)b * 3 + 2] = acc[2];
        }
    }
}

extern "C" void kernel_launch(void* const* d_in, const int* in_sizes, int n_in,
                              void* d_out, int out_size, void* d_ws, size_t ws_size,
                              hipStream_t stream) {
    const float* h    = (const float*)d_in[0];
    const float* cell = (const float*)d_in[1];
    const float* w    = (const float*)d_in[2];
    const float* bias = (const float*)d_in[3];
    float* out = (float*)d_out;
    const int bq = in_sizes[0] / (C_H * KSC);

    gsr_kernel<<<NBLOCKS, NTHREADS, 0, stream>>>(h, cell, w, bias, out, bq);
}

// Round 2
// 679.319 us; speedup vs baseline: 1.0160x; 1.0160x over previous
//
#include <hip/hip_runtime.h>
#include <math.h>

// GaussianScaleReadout: y[b,o] = sum_k alpha[b,k] * (sum_c h[b,c,k]*w[k,o,c] + bias[k,o])
// Memory-bound on h (512 MiB, read exactly once). One wave handles 4 queries per
// iteration: 16 KiB contiguous -> 16 independent dwordx4 loads in flight (4x the
// MLP of the 1-query version), 12 independent shuffle-reduction chains (latency
// hidden by ILP), softmax computed under the load shadow.
//
// Index algebra (h inner layout [c,k], k fastest; float4 j = i*64+lane of the
// 4-query block): g = i>>2 (query), k = (lane&1)*4+e, c = (i&3)*32+(lane>>1).
// Weights (12 KiB) live in 48 VGPRs per lane, loaded once per wave.

#define C_H   128
#define KSC   8

constexpr int NBLOCKS  = 2048;   // grid-stride
constexpr int NTHREADS = 256;    // 4 waves/block
constexpr int NWAVES   = NBLOCKS * NTHREADS / 64;  // 8192

__global__ __launch_bounds__(NTHREADS)
void gsr_kernel(const float* __restrict__ h,      // [BQ, C_H, K]
                const float* __restrict__ cell,   // [BQ, 2]
                const float* __restrict__ w,      // [K, 3, C_H]
                const float* __restrict__ bias,   // [K, 3]
                float* __restrict__ out,          // [BQ, 3]
                int bq)
{
    const int lane   = threadIdx.x & 63;
    const int waveId = blockIdx.x * (NTHREADS / 64) + (threadIdx.x >> 6);

    // ---- one-time per-wave weight preload into registers ----
    const int kbase = (lane & 1) * 4;   // this lane's k-subset base (0 or 4)
    const int chalf = lane >> 1;
    float wreg[4][4][3];                // [i&3][e][o]
    #pragma unroll
    for (int i4 = 0; i4 < 4; ++i4) {
        #pragma unroll
        for (int e = 0; e < 4; ++e) {
            const int k = kbase + e;
            const int c = i4 * 32 + chalf;
            #pragma unroll
            for (int o = 0; o < 3; ++o)
                wreg[i4][e][o] = w[k * (3*C_H) + o * C_H + c];
        }
    }
    // bias fragments: lane 0 covers k=0..3, lane 1 covers k=4..7, others zero;
    // the cross-lane reduction sums them exactly once.
    float breg[4][3];
    #pragma unroll
    for (int e = 0; e < 4; ++e)
        #pragma unroll
        for (int o = 0; o < 3; ++o)
            breg[e][o] = (lane < 2) ? bias[(kbase + e) * 3 + o] : 0.0f;

    const float inv_two_sigma_sq = 0.78125f;             // 1 / (2*0.8^2)
    const float log_2_over_inp   = -4.8520302639196171f; // log(2/256)
    const float seven_over_log30 = 2.0580814087539097f;  // 7 / log(30)

    const int ngrp = bq >> 2;            // groups of 4 queries
    const float2* cell2 = (const float2*)cell;

    for (int grp = waveId; grp < ngrp; grp += NWAVES) {
        const int b4 = grp << 2;

        // ---- issue all 16 h-loads up front (16 KiB contiguous, coalesced) ----
        const float4* hp = (const float4*)(h + (size_t)b4 * (C_H * KSC));
        float4 hv[16];
        #pragma unroll
        for (int i = 0; i < 16; ++i)
            hv[i] = hp[i * 64 + lane];

        // ---- tau + alpha for the 4 queries (computed under load shadow) ----
        float al[4][4];   // [g][e]: alpha for k = kbase+e
        float acc[4][3];
        #pragma unroll
        for (int g = 0; g < 4; ++g) {
            const float2 cg = cell2[b4 + g];
            const float geo = fmaxf(sqrtf(cg.x * cg.y), 1e-10f);
            const float log_s = log_2_over_inp - __logf(geo);
            float tau = seven_over_log30 * log_s;
            tau = fminf(fmaxf(tau, 0.0f), 7.0f);

            float ek[8], s = 0.0f;
            #pragma unroll
            for (int k = 0; k < 8; ++k) {
                const float d = (float)k - tau;
                ek[k] = __expf(-d * d * inv_two_sigma_sq);
                s += ek[k];
            }
            const float inv = 1.0f / s;
            #pragma unroll
            for (int e = 0; e < 4; ++e)
                al[g][e] = ((lane & 1) ? ek[4 + e] : ek[e]) * inv;

            // bias into accumulator init (zero except lanes 0/1)
            #pragma unroll
            for (int o = 0; o < 3; ++o) {
                acc[g][o] = al[g][0] * breg[0][o];
                #pragma unroll
                for (int e = 1; e < 4; ++e)
                    acc[g][o] = fmaf(al[g][e], breg[e][o], acc[g][o]);
            }
        }

        // ---- accumulate ----
        #pragma unroll
        for (int i = 0; i < 16; ++i) {
            const int g  = i >> 2;
            const int i4 = i & 3;
            const float he[4] = {hv[i].x, hv[i].y, hv[i].z, hv[i].w};
            #pragma unroll
            for (int e = 0; e < 4; ++e) {
                const float ha = he[e] * al[g][e];
                #pragma unroll
                for (int o = 0; o < 3; ++o)
                    acc[g][o] = fmaf(ha, wreg[i4][e][o], acc[g][o]);
            }
        }

        // ---- 12 independent butterfly reductions over 64 lanes ----
        #pragma unroll
        for (int off = 32; off > 0; off >>= 1) {
            #pragma unroll
            for (int g = 0; g < 4; ++g) {
                acc[g][0] += __shfl_xor(acc[g][0], off, 64);
                acc[g][1] += __shfl_xor(acc[g][1], off, 64);
                acc[g][2] += __shfl_xor(acc[g][2], off, 64);
            }
        }

        // ---- lane 0 stores 12 contiguous floats as 3 x float4 ----
        if (lane == 0) {
            float4* op = (float4*)(out + (size_t)b4 * 3);
            op[0] = make_float4(acc[0][0], acc[0][1], acc[0][2], acc[1][0]);
            op[1] = make_float4(acc[1][1], acc[1][2], acc[2][0], acc[2][1]);
            op[2] = make_float4(acc[2][2], acc[3][0], acc[3][1], acc[3][2]);
        }
    }
}

extern "C" void kernel_launch(void* const* d_in, const int* in_sizes, int n_in,
                              void* d_out, int out_size, void* d_ws, size_t ws_size,
                              hipStream_t stream) {
    const float* h    = (const float*)d_in[0];
    const float* cell = (const float*)d_in[1];
    const float* w    = (const float*)d_in[2];
    const float* bias = (const float*)d_in[3];
    float* out = (float*)d_out;
    const int bq = in_sizes[0] / (C_H * KSC);

    gsr_kernel<<<NBLOCKS, NTHREADS, 0, stream>>>(h, cell, w, bias, out, bq);
}